// Round 8
// baseline (130.533 us; speedup 1.0000x reference)
//
#include <hip/hip_runtime.h>
#include <hip/hip_fp16.h>
#include <stdint.h>

// Problem constants: B=32, N=2048, L=32768, D_IN=4, D=64
#define B_ 32
#define N_ 2048
#define L_ 32768

// Single fused kernel, ZERO LDS. Per block:
//  1. issue edge-index + line_param loads (latency hidden under fold)
//  2. WAVE 0 folds the whole weight chain (lane f owns feature f: 9
//     length-64 dots, W1 reads coalesced, W_embed/b_embed uniform s_load)
//     and writes a BLOCK-PRIVATE 48 B/feature splat-half2 table into the
//     workspace (2 KB stride per block -> no cross-block coherence needed).
//  3. __syncthreads(): drains wave0's vmcnt -> table visible in L2.
//  4. main loop (64 features): weights stream back on the SCALAR pipe via
//     inline-asm s_load_dwordx4 (compiler won't select SMEM past an
//     in-kernel store to the same buffer, so we force it). 2 edges per
//     half2 slot, 11 VOP3P per feature. Node gathers straight from L2.
// K$ staleness note: nothing s_loads the table region before our write, and
// table contents are identical across graph iterations -> stale == correct.
// Table record (12 dwords): [0..3]=wc1[i][f] splat, [4..7]=wc2[i][f] splat,
// [8]=bias splat, [9]=W2[f][2] splat, [10]=W2[f][3] splat, [11]=pad.

typedef unsigned int u32x4 __attribute__((ext_vector_type(4)));

static __device__ __forceinline__ __half2 pkrn(float a, float b) {
    return __float22half2_rn(make_float2(a, b));
}

static __device__ __forceinline__ __half2 pkmax(__half2 a, __half2 b) {
    __half2 r;
    asm("v_pk_max_f16 %0, %1, %2" : "=v"(r) : "v"(a), "v"(b));
    return r;
}

static __device__ __forceinline__ unsigned int h2u(__half2 h) {
    union { __half2 h; unsigned int u; } c; c.h = h; return c.u;
}

static __device__ __forceinline__ __half2 u2h(unsigned int u) {
    union { unsigned int u; __half2 h; } c; c.u = u; return c.h;
}

__global__ __launch_bounds__(256, 8) void fused_kernel(
    const float4* __restrict__ pred_node,  // (B*N) float4 rows
    const float* __restrict__ W_embed, const float* __restrict__ b_embed,
    const float* __restrict__ W1, const float* __restrict__ b1,
    const float* __restrict__ W2, const float* __restrict__ b2,
    const int* __restrict__ esrc, const int* __restrict__ edst,
    const float2* __restrict__ lp2,        // line_param as float2 pairs
    unsigned int* __restrict__ wstab,      // workspace: 2 KB per block
    float4* __restrict__ out) {
    const int tid = threadIdx.x;
    const int bid = blockIdx.x;          // 0..2047
    const int x = bid & 7;               // XCD (dispatch round-robin heuristic)
    const int i = bid >> 3;              // 0..255
    const int b = x + 8 * (i >> 6);      // batch 0..31: 4 batches/XCD, pinned
    const int j = i & 63;                // chunk within batch (64 x 512 edges)
    const int ebase = b * L_ + j * 512 + tid;  // edge0; edge1 = ebase+256

    // ---- edge indices + lp early: HBM latency hides under the fold ----
    int s0 = esrc[ebase], s1 = esrc[ebase + 256];
    int t0 = edst[ebase], t1 = edst[ebase + 256];
    float2 lp0 = lp2[(size_t)ebase * 2];
    float2 lp1 = lp2[(size_t)(ebase + 256) * 2];

    unsigned int* tbl = wstab + (size_t)bid * 512;  // block-private 2 KB

    // ---- wave 0: fold weights, lane f owns feature f ----
    if (tid < 64) {
        const int f = tid;
        float at0 = 0.f, at1 = 0.f, at2 = 0.f, at3 = 0.f;  // wc1[i][f]
        float ab0 = 0.f, ab1 = 0.f, ab2 = 0.f, ab3 = 0.f;  // wc2[i][f]
        float bia = 0.f;
#pragma unroll 8
        for (int k = 0; k < 64; ++k) {
            float wt = W1[k * 64 + f];           // coalesced across lanes
            float wb = W1[(64 + k) * 64 + f];
            float e0 = W_embed[k];               // wave-uniform -> s_load
            float e1 = W_embed[64 + k];
            float e2 = W_embed[128 + k];
            float e3 = W_embed[192 + k];
            at0 = fmaf(e0, wt, at0);
            at1 = fmaf(e1, wt, at1);
            at2 = fmaf(e2, wt, at2);
            at3 = fmaf(e3, wt, at3);
            ab0 = fmaf(e0, wb, ab0);
            ab1 = fmaf(e1, wb, ab1);
            ab2 = fmaf(e2, wb, ab2);
            ab3 = fmaf(e3, wb, ab3);
            bia = fmaf(b_embed[k], wt + wb, bia);
        }
        bia += b1[f];
        float c2 = W2[f * 4 + 2], c3 = W2[f * 4 + 3];

        u32x4 q0, q1, q2;
        q0.x = h2u(pkrn(at0, at0));
        q0.y = h2u(pkrn(at1, at1));
        q0.z = h2u(pkrn(at2, at2));
        q0.w = h2u(pkrn(at3, at3));
        q1.x = h2u(pkrn(ab0, ab0));
        q1.y = h2u(pkrn(ab1, ab1));
        q1.z = h2u(pkrn(ab2, ab2));
        q1.w = h2u(pkrn(ab3, ab3));
        q2.x = h2u(pkrn(bia, bia));
        q2.y = h2u(pkrn(c2, c2));
        q2.z = h2u(pkrn(c3, c3));
        q2.w = 0u;
        u32x4* rec = reinterpret_cast<u32x4*>(tbl + f * 12);  // 48 B, 16-B aligned
        rec[0] = q0;
        rec[1] = q1;
        rec[2] = q2;
    }

    // ---- gathers (independent of table, issued before barrier) ----
    const float4* pnb = pred_node + b * N_;
    float4 vs0 = pnb[s0];
    float4 vs1 = pnb[s1];
    float4 vt0 = pnb[t0];
    float4 vt1 = pnb[t1];

    __half2 px0 = pkrn(vs0.x, vs1.x);
    __half2 px1 = pkrn(vs0.y, vs1.y);
    __half2 px2 = pkrn(vs0.z, vs1.z);
    __half2 px3 = pkrn(vs0.w, vs1.w);
    __half2 px4 = pkrn(vt0.x, vt1.x);
    __half2 px5 = pkrn(vt0.y, vt1.y);
    __half2 px6 = pkrn(vt0.z, vt1.z);
    __half2 px7 = pkrn(vt0.w, vt1.w);

    __syncthreads();  // wave0's table stores drained to L2 (vmcnt(0)+barrier)

    const __half2 zero = u2h(0u);
    __half2 acc2 = zero, acc3 = zero;
    const uint64_t tbase = (uint64_t)(uintptr_t)tbl;

#pragma unroll 2
    for (int f = 0; f < 64; ++f) {
        u32x4 q0, q1, q2;
        uint64_t addr = tbase + (uint64_t)(f * 48);
        asm volatile(
            "s_load_dwordx4 %0, %3, 0x0\n\t"
            "s_load_dwordx4 %1, %3, 0x10\n\t"
            "s_load_dwordx4 %2, %3, 0x20\n\t"
            "s_waitcnt lgkmcnt(0)"
            : "=&s"(q0), "=&s"(q1), "=&s"(q2)
            : "s"(addr)
            : "memory");
        __half2 h = u2h(q2.x);                  // bias
        h = __hfma2(px0, u2h(q0.x), h);
        h = __hfma2(px1, u2h(q0.y), h);
        h = __hfma2(px2, u2h(q0.z), h);
        h = __hfma2(px3, u2h(q0.w), h);
        h = __hfma2(px4, u2h(q1.x), h);
        h = __hfma2(px5, u2h(q1.y), h);
        h = __hfma2(px6, u2h(q1.z), h);
        h = __hfma2(px7, u2h(q1.w), h);
        h = pkmax(h, zero);                     // relu, single VOP3P
        acc2 = __hfma2(h, u2h(q2.y), acc2);
        acc3 = __hfma2(h, u2h(q2.z), acc3);
    }

    // ---- epilogue (lp already in registers) ----
    float bias2 = b2[2], bias3 = b2[3];  // uniform -> s_load
    out[ebase] = make_float4(lp0.x, lp0.y,
                             bias2 + __low2float(acc2),
                             bias3 + __low2float(acc3));
    out[ebase + 256] = make_float4(lp1.x, lp1.y,
                                   bias2 + __high2float(acc2),
                                   bias3 + __high2float(acc3));
}

extern "C" void kernel_launch(void* const* d_in, const int* in_sizes, int n_in,
                              void* d_out, int out_size, void* d_ws, size_t ws_size,
                              hipStream_t stream) {
    const float* pred_node = (const float*)d_in[0];   // (B,N,4)
    const float* line_param = (const float*)d_in[1];  // (B,L,4)
    const float* W_embed = (const float*)d_in[2];     // (4,64)
    const float* b_embed = (const float*)d_in[3];     // (64,)
    const float* W1 = (const float*)d_in[4];          // (128,64)
    const float* b1 = (const float*)d_in[5];          // (64,)
    const float* W2 = (const float*)d_in[6];          // (64,4)
    const float* b2 = (const float*)d_in[7];          // (4,)
    const int* esrc = (const int*)d_in[8];            // (B,L)
    const int* edst = (const int*)d_in[9];            // (B,L)
    float* out = (float*)d_out;                       // (B,L,4)

    fused_kernel<<<2048, 256, 0, stream>>>((const float4*)pred_node,
                                           W_embed, b_embed, W1, b1, W2, b2,
                                           esrc, edst,
                                           (const float2*)line_param,
                                           (unsigned int*)d_ws,
                                           (float4*)out);
}

// Round 9
// 109.363 us; speedup vs baseline: 1.1936x; 1.1936x over previous
//
#include <hip/hip_runtime.h>
#include <hip/hip_fp16.h>
#include <stdint.h>

// Problem constants: B=32, N=2048, L=32768, D_IN=4, D=64
#define B_ 32
#define N_ 2048
#define L_ 32768

// Workspace: splatted half2 weight table, 64 features x 12 half2 (48 B each):
//   [f*12 + 0..3] : {wc1[i][f], wc1[i][f]} for input dim i of src node
//   [f*12 + 4..7] : same for dst node (wc2)
//   [f*12 + 8]    : {bias[f], bias[f]}   (b_embed@(W1_top+W1_bot)+b1)
//   [f*12 + 9]    : {W2[f][2], W2[f][2]}
//   [f*12 + 10]   : {W2[f][3], W2[f][3]}
//   [f*12 + 11]   : pad
// wc1 = W_embed@W1_top, wc2 = W_embed@W1_bot.

static __device__ __forceinline__ __half2 pkrn(float a, float b) {
    return __float22half2_rn(make_float2(a, b));
}

static __device__ __forceinline__ __half2 pkmax(__half2 a, __half2 b) {
    __half2 r;
    asm("v_pk_max_f16 %0, %1, %2" : "=v"(r) : "v"(a), "v"(b));
    return r;
}

static __device__ __forceinline__ __half2 bits_h2(float x) {
    union { float f; __half2 h; } u;
    u.f = x;
    return u.h;
}

// ---------------- Kernel A: fold linears, emit splatted half2 table ---------
// (verbatim from the verified round-2 run)
__global__ __launch_bounds__(512) void prep_kernel(
    const float* __restrict__ W_embed, const float* __restrict__ b_embed,
    const float* __restrict__ W1, const float* __restrict__ b1,
    const float* __restrict__ W2, __half2* __restrict__ wh) {
    __shared__ float sacc[64][8];
    __shared__ float sbias[64];
    int tid = threadIdx.x;
    int d = tid & 63;          // feature column (lane)
    int i = (tid >> 6) & 3;    // input dim (wave-uniform)
    int half_ = tid >> 8;      // 0 = top (src), 1 = bot (dst)

    const float* w1base = W1 + (half_ ? 64 * 64 : 0);
    float acc = 0.f;
#pragma unroll
    for (int k = 0; k < 64; ++k) {
        acc = fmaf(W_embed[i * 64 + k], w1base[k * 64 + d], acc);
    }
    sacc[d][half_ * 4 + i] = acc;

    if (tid < 64) {  // merged bias
        float bb = 0.f;
#pragma unroll
        for (int k = 0; k < 64; ++k) {
            bb = fmaf(b_embed[k], W1[k * 64 + d] + W1[(64 + k) * 64 + d], bb);
        }
        sbias[d] = bb + b1[d];
    }
    __syncthreads();

    if (tid < 64) {  // pack feature f = tid, everything splatted {v,v}
#pragma unroll
        for (int k = 0; k < 8; ++k) {
            float v = sacc[tid][k];
            wh[tid * 12 + k] = pkrn(v, v);
        }
        float bv = sbias[tid];
        wh[tid * 12 + 8] = pkrn(bv, bv);
        float c2 = W2[tid * 4 + 2];
        float c3 = W2[tid * 4 + 3];
        wh[tid * 12 + 9] = pkrn(c2, c2);
        wh[tid * 12 + 10] = pkrn(c3, c3);
        wh[tid * 12 + 11] = pkrn(0.f, 0.f);
    }
}

// ---------------- Kernel B: per-edge, no-LDS, 4 edges/thread ----------------
// 1024 blocks x 256 threads, (256,8) -> 8 waves/SIMD. No LDS. Node gathers
// straight from L2 (batch pinned to one XCD via bid&7). Weights wave-uniform
// -> s_load_dwordx4; feature loop FULLY unrolled so the compiler can batch
// and pipeline the scalar loads across features. 4 edges/thread = 2
// independent half2 acc chains (ILP) and half the per-edge scalar traffic.
__global__ __launch_bounds__(256, 8) void edge_kernel(
    const float4* __restrict__ pred_node,  // (B*N) float4 rows
    const __half2* __restrict__ wh,
    const int* __restrict__ esrc, const int* __restrict__ edst,
    const float4* __restrict__ lp4,        // line_param as float4 rows
    const float* __restrict__ b2,
    float4* __restrict__ out) {
    const int tid = threadIdx.x;
    const int bid = blockIdx.x;          // 0..1023
    const int x = bid & 7;               // XCD (dispatch round-robin heuristic)
    const int i = bid >> 3;              // 0..127
    const int b = x + 8 * (i >> 5);      // batch 0..31: 4 batches/XCD, pinned
    const int j = i & 31;                // chunk within batch (32 x 1024 edges)
    const int ebase = b * L_ + j * 1024 + tid;  // edges at ebase + p*256

    // ---- edge indices (coalesced) ----
    int sa[4], ta[4];
#pragma unroll
    for (int p = 0; p < 4; ++p) {
        sa[p] = esrc[ebase + p * 256];
        ta[p] = edst[ebase + p * 256];
    }

    // ---- gather node pairs from L2; pack 2 edges per half2 slot ----
    const float4* pnb = pred_node + b * N_;
    __half2 px[2][8];
#pragma unroll
    for (int pr = 0; pr < 2; ++pr) {
        float4 s0 = pnb[sa[2 * pr]];
        float4 s1 = pnb[sa[2 * pr + 1]];
        float4 t0 = pnb[ta[2 * pr]];
        float4 t1 = pnb[ta[2 * pr + 1]];
        px[pr][0] = pkrn(s0.x, s1.x);
        px[pr][1] = pkrn(s0.y, s1.y);
        px[pr][2] = pkrn(s0.z, s1.z);
        px[pr][3] = pkrn(s0.w, s1.w);
        px[pr][4] = pkrn(t0.x, t1.x);
        px[pr][5] = pkrn(t0.y, t1.y);
        px[pr][6] = pkrn(t0.z, t1.z);
        px[pr][7] = pkrn(t0.w, t1.w);
    }

    const __half2 zero = pkrn(0.f, 0.f);
    __half2 acc2[2] = {zero, zero};
    __half2 acc3[2] = {zero, zero};

#pragma unroll
    for (int f = 0; f < 64; ++f) {  // FULL unroll: compile-time s_load offsets
        const float4* wv = reinterpret_cast<const float4*>(wh) + f * 3;
        float4 q0 = wv[0], q1 = wv[1], q2 = wv[2];
        __half2 w0 = bits_h2(q0.x), w1 = bits_h2(q0.y);
        __half2 w2w = bits_h2(q0.z), w3w = bits_h2(q0.w);
        __half2 w4 = bits_h2(q1.x), w5 = bits_h2(q1.y);
        __half2 w6w = bits_h2(q1.z), w7w = bits_h2(q1.w);
        __half2 bs = bits_h2(q2.x);
        __half2 c2 = bits_h2(q2.y), c3 = bits_h2(q2.z);
#pragma unroll
        for (int pr = 0; pr < 2; ++pr) {
            __half2 h = bs;
            h = __hfma2(px[pr][0], w0, h);
            h = __hfma2(px[pr][1], w1, h);
            h = __hfma2(px[pr][2], w2w, h);
            h = __hfma2(px[pr][3], w3w, h);
            h = __hfma2(px[pr][4], w4, h);
            h = __hfma2(px[pr][5], w5, h);
            h = __hfma2(px[pr][6], w6w, h);
            h = __hfma2(px[pr][7], w7w, h);
            h = pkmax(h, zero);  // relu, single VOP3P
            acc2[pr] = __hfma2(h, c2, acc2[pr]);
            acc3[pr] = __hfma2(h, c3, acc3[pr]);
        }
    }

    // ---- epilogue: lp loads late (fewer live VGPRs in main loop) ----
    float bias2 = b2[2], bias3 = b2[3];  // uniform -> s_load
#pragma unroll
    for (int p = 0; p < 4; ++p) {
        int e = ebase + p * 256;
        float4 lp = lp4[e];              // full row: same sectors, one load
        int pr = p >> 1;
        float r2 = (p & 1) ? __high2float(acc2[pr]) : __low2float(acc2[pr]);
        float r3 = (p & 1) ? __high2float(acc3[pr]) : __low2float(acc3[pr]);
        out[e] = make_float4(lp.x, lp.y, bias2 + r2, bias3 + r3);
    }
}

extern "C" void kernel_launch(void* const* d_in, const int* in_sizes, int n_in,
                              void* d_out, int out_size, void* d_ws, size_t ws_size,
                              hipStream_t stream) {
    const float* pred_node = (const float*)d_in[0];   // (B,N,4)
    const float* line_param = (const float*)d_in[1];  // (B,L,4)
    const float* W_embed = (const float*)d_in[2];     // (4,64)
    const float* b_embed = (const float*)d_in[3];     // (64,)
    const float* W1 = (const float*)d_in[4];          // (128,64)
    const float* b1 = (const float*)d_in[5];          // (64,)
    const float* W2 = (const float*)d_in[6];          // (64,4)
    const float* b2 = (const float*)d_in[7];          // (4,)
    const int* esrc = (const int*)d_in[8];            // (B,L)
    const int* edst = (const int*)d_in[9];            // (B,L)
    float* out = (float*)d_out;                       // (B,L,4)

    __half2* wh = (__half2*)d_ws;

    prep_kernel<<<1, 512, 0, stream>>>(W_embed, b_embed, W1, b1, W2, wh);
    edge_kernel<<<1024, 256, 0, stream>>>((const float4*)pred_node, wh,
                                          esrc, edst,
                                          (const float4*)line_param, b2,
                                          (float4*)out);
}

// Round 10
// 106.320 us; speedup vs baseline: 1.2277x; 1.0286x over previous
//
#include <hip/hip_runtime.h>
#include <hip/hip_fp16.h>
#include <stdint.h>

// Problem constants: B=32, N=2048, L=32768, D_IN=4, D=64
#define B_ 32
#define N_ 2048
#define L_ 32768

// Workspace: splatted half2 weight table, 64 features x 12 half2 (48 B each):
//   [f*12 + 0..3] : {wc1[i][f], wc1[i][f]} for input dim i of src node
//   [f*12 + 4..7] : same for dst node (wc2)
//   [f*12 + 8]    : {bias[f], bias[f]}   (b_embed@(W1_top+W1_bot)+b1)
//   [f*12 + 9]    : {W2[f][2], W2[f][2]}
//   [f*12 + 10]   : {W2[f][3], W2[f][3]}
//   [f*12 + 11]   : pad
// wc1 = W_embed@W1_top, wc2 = W_embed@W1_bot.

static __device__ __forceinline__ __half2 pkrn(float a, float b) {
    return __float22half2_rn(make_float2(a, b));
}

static __device__ __forceinline__ __half2 pkmax(__half2 a, __half2 b) {
    __half2 r;
    asm("v_pk_max_f16 %0, %1, %2" : "=v"(r) : "v"(a), "v"(b));
    return r;
}

static __device__ __forceinline__ unsigned int h2u(__half2 h) {
    union { __half2 h; unsigned int u; } c; c.h = h; return c.u;
}

static __device__ __forceinline__ __half2 u2h(unsigned int u) {
    union { unsigned int u; __half2 h; } c; c.u = u; return c.h;
}

// {lo16(A), lo16(B)} and {hi16(A), hi16(B)} via v_perm_b32.
// perm(a,b,sel): byte pool = {b bytes 0-3, a bytes 4-7}.
static __device__ __forceinline__ __half2 lo_lo(unsigned int A, unsigned int B) {
    return u2h(__builtin_amdgcn_perm(A, B, 0x01000504u));
}
static __device__ __forceinline__ __half2 hi_hi(unsigned int A, unsigned int B) {
    return u2h(__builtin_amdgcn_perm(A, B, 0x03020706u));
}

// ---------------- Kernel A: fold linears, emit splatted half2 table ---------
// (verbatim from the verified round-2 run)
__global__ __launch_bounds__(512) void prep_kernel(
    const float* __restrict__ W_embed, const float* __restrict__ b_embed,
    const float* __restrict__ W1, const float* __restrict__ b1,
    const float* __restrict__ W2, __half2* __restrict__ wh) {
    __shared__ float sacc[64][8];
    __shared__ float sbias[64];
    int tid = threadIdx.x;
    int d = tid & 63;          // feature column (lane)
    int i = (tid >> 6) & 3;    // input dim (wave-uniform)
    int half_ = tid >> 8;      // 0 = top (src), 1 = bot (dst)

    const float* w1base = W1 + (half_ ? 64 * 64 : 0);
    float acc = 0.f;
#pragma unroll
    for (int k = 0; k < 64; ++k) {
        acc = fmaf(W_embed[i * 64 + k], w1base[k * 64 + d], acc);
    }
    sacc[d][half_ * 4 + i] = acc;

    if (tid < 64) {  // merged bias
        float bb = 0.f;
#pragma unroll
        for (int k = 0; k < 64; ++k) {
            bb = fmaf(b_embed[k], W1[k * 64 + d] + W1[(64 + k) * 64 + d], bb);
        }
        sbias[d] = bb + b1[d];
    }
    __syncthreads();

    if (tid < 64) {  // pack feature f = tid, everything splatted {v,v}
#pragma unroll
        for (int k = 0; k < 8; ++k) {
            float v = sacc[tid][k];
            wh[tid * 12 + k] = pkrn(v, v);
        }
        float bv = sbias[tid];
        wh[tid * 12 + 8] = pkrn(bv, bv);
        float c2 = W2[tid * 4 + 2];
        float c3 = W2[tid * 4 + 3];
        wh[tid * 12 + 9] = pkrn(c2, c2);
        wh[tid * 12 + 10] = pkrn(c3, c3);
        wh[tid * 12 + 11] = pkrn(0.f, 0.f);
    }
}

// ---------------- Kernel B: half-packed LDS node table, 8 waves/SIMD --------
// 2048 blocks x 256 threads, (256,8). Node table staged in LDS as packed
// half: uint2 {h2(x,y), h2(z,w)} per node = 16 KB -> 8 blocks/CU (128 KB).
// Random gathers hit LDS banks (fast divergent access) instead of the L1/TA
// port (which serializes ~64 address-divergent probes per instruction).
// Edge-pair interleave via v_perm_b32 (conversion already paid at staging).
// Weights stream on the scalar pipe (s_load, compiler-selected). lp4
// prefetched before the main loop to overlap the final HBM round-trip.
__global__ __launch_bounds__(256, 8) void edge_kernel(
    const float4* __restrict__ pred_node,  // (B*N) float4 rows
    const __half2* __restrict__ wh,
    const int* __restrict__ esrc, const int* __restrict__ edst,
    const float4* __restrict__ lp4,        // line_param as float4 rows
    const float* __restrict__ b2,
    float4* __restrict__ out) {
    __shared__ uint2 spn[N_];   // 16 KB: half-packed node table

    const int tid = threadIdx.x;
    const int bid = blockIdx.x;          // 0..2047
    const int x = bid & 7;               // XCD (dispatch round-robin heuristic)
    const int i = bid >> 3;              // 0..255
    const int b = x + 8 * (i >> 6);      // batch 0..31: 4 batches/XCD, pinned
    const int j = i & 63;                // chunk within batch (64 x 512 edges)
    const int ebase = b * L_ + j * 512 + tid;  // edge0; edge1 = ebase+256

    // ---- edge indices + lp prefetch (latency hides under staging) ----
    int s0 = esrc[ebase], s1 = esrc[ebase + 256];
    int t0 = edst[ebase], t1 = edst[ebase + 256];
    float4 lpa = lp4[ebase];
    float4 lpb = lp4[ebase + 256];

    // ---- stage pred_node[b] into LDS as packed half (coalesced) ----
    const float4* pnb = pred_node + b * N_;
#pragma unroll
    for (int q = 0; q < 8; ++q) {
        int idx = tid + q * 256;
        float4 v = pnb[idx];
        spn[idx] = make_uint2(h2u(pkrn(v.x, v.y)), h2u(pkrn(v.z, v.w)));
    }

    __syncthreads();  // table ready

    // ---- gather 4 nodes (LDS banked: fast under address divergence) ----
    uint2 a0 = spn[s0];   // edge0 src {xy, zw}
    uint2 a1 = spn[s1];   // edge1 src
    uint2 d0 = spn[t0];   // edge0 dst
    uint2 d1 = spn[t1];   // edge1 dst

    // ---- edge-pair interleave: one v_perm each ----
    __half2 px0 = lo_lo(a0.x, a1.x);   // {e0.x, e1.x}
    __half2 px1 = hi_hi(a0.x, a1.x);   // {e0.y, e1.y}
    __half2 px2 = lo_lo(a0.y, a1.y);   // {e0.z, e1.z}
    __half2 px3 = hi_hi(a0.y, a1.y);   // {e0.w, e1.w}
    __half2 px4 = lo_lo(d0.x, d1.x);
    __half2 px5 = hi_hi(d0.x, d1.x);
    __half2 px6 = lo_lo(d0.y, d1.y);
    __half2 px7 = hi_hi(d0.y, d1.y);

    const __half2 zero = u2h(0u);
    __half2 acc2 = zero, acc3 = zero;

#pragma unroll 4
    for (int f = 0; f < 64; ++f) {  // weights wave-uniform -> s_load_dwordx4
        const float4* wv = reinterpret_cast<const float4*>(wh) + f * 3;
        float4 q0 = wv[0], q1 = wv[1], q2 = wv[2];
        __half2 h = u2h(__float_as_uint(q2.x));          // bias
        h = __hfma2(px0, u2h(__float_as_uint(q0.x)), h);
        h = __hfma2(px1, u2h(__float_as_uint(q0.y)), h);
        h = __hfma2(px2, u2h(__float_as_uint(q0.z)), h);
        h = __hfma2(px3, u2h(__float_as_uint(q0.w)), h);
        h = __hfma2(px4, u2h(__float_as_uint(q1.x)), h);
        h = __hfma2(px5, u2h(__float_as_uint(q1.y)), h);
        h = __hfma2(px6, u2h(__float_as_uint(q1.z)), h);
        h = __hfma2(px7, u2h(__float_as_uint(q1.w)), h);
        h = pkmax(h, zero);                              // relu
        acc2 = __hfma2(h, u2h(__float_as_uint(q2.y)), acc2);
        acc3 = __hfma2(h, u2h(__float_as_uint(q2.z)), acc3);
    }

    // ---- epilogue (lp already in registers) ----
    float bias2 = b2[2], bias3 = b2[3];  // uniform -> s_load
    out[ebase] = make_float4(lpa.x, lpa.y,
                             bias2 + __low2float(acc2),
                             bias3 + __low2float(acc3));
    out[ebase + 256] = make_float4(lpb.x, lpb.y,
                                   bias2 + __high2float(acc2),
                                   bias3 + __high2float(acc3));
}

extern "C" void kernel_launch(void* const* d_in, const int* in_sizes, int n_in,
                              void* d_out, int out_size, void* d_ws, size_t ws_size,
                              hipStream_t stream) {
    const float* pred_node = (const float*)d_in[0];   // (B,N,4)
    const float* line_param = (const float*)d_in[1];  // (B,L,4)
    const float* W_embed = (const float*)d_in[2];     // (4,64)
    const float* b_embed = (const float*)d_in[3];     // (64,)
    const float* W1 = (const float*)d_in[4];          // (128,64)
    const float* b1 = (const float*)d_in[5];          // (64,)
    const float* W2 = (const float*)d_in[6];          // (64,4)
    const float* b2 = (const float*)d_in[7];          // (4,)
    const int* esrc = (const int*)d_in[8];            // (B,L)
    const int* edst = (const int*)d_in[9];            // (B,L)
    float* out = (float*)d_out;                       // (B,L,4)

    __half2* wh = (__half2*)d_ws;

    prep_kernel<<<1, 512, 0, stream>>>(W_embed, b_embed, W1, b1, W2, wh);
    edge_kernel<<<2048, 256, 0, stream>>>((const float4*)pred_node, wh,
                                          esrc, edst,
                                          (const float4*)line_param, b2,
                                          (float4*)out);
}